// Round 1
// baseline (21.941 us; speedup 1.0000x reference)
//
#include <hip/hip_runtime.h>
#include <math.h>

constexpr int NB = 8;    // batch
constexpr int NF = 32;   // features
constexpr int NN = 512;  // nodes
constexpr int NH = 8;    // hidden

// ---------------------------------------------------------------------------
// Kernel 1: per (b,n) precompute
//   u[b,n,k] = sum_f emb[b,f,n] * W1[f,k]
//   v[b,n,k] = sum_f emb[b,f,n] * W1[F+f,k] + sw[b,n]*W1[2F,k] + b1[k]
//   sw[b,n]  = (colsum0[n] - adj[b,n,n]) / (N-1),  colsum0[n] = sum_k adj[0,k,n]
// ---------------------------------------------------------------------------
__global__ __launch_bounds__(256) void uv_kernel(
    const float* __restrict__ adj, const float* __restrict__ emb,
    const float* __restrict__ W1, const float* __restrict__ b1,
    float* __restrict__ u, float* __restrict__ v)
{
    const int idx = blockIdx.x * 256 + threadIdx.x;   // [0, B*N)
    const int b = idx / NN;
    const int n = idx % NN;

    // column sum of batch-0 adjacency, column n (coalesced across lanes)
    float cs = 0.f;
    #pragma unroll 16
    for (int k = 0; k < NN; ++k)
        cs += adj[(size_t)k * NN + n];

    const float dg = adj[((size_t)b * NN + n) * NN + n];
    const float sw = (cs - dg) * (1.0f / (float)(NN - 1));

    float uo[NH], vo[NH];
    #pragma unroll
    for (int k = 0; k < NH; ++k) {
        uo[k] = 0.f;
        vo[k] = b1[k] + sw * W1[2 * NF * NH + k];
    }

    // W1 is uniform across the wave -> scalar-cached loads
    for (int f = 0; f < NF; ++f) {
        const float e = emb[((size_t)b * NF + f) * NN + n];   // coalesced in n
        #pragma unroll
        for (int k = 0; k < NH; ++k) {
            uo[k] = fmaf(e, W1[f * NH + k],        uo[k]);
            vo[k] = fmaf(e, W1[(NF + f) * NH + k], vo[k]);
        }
    }

    float4* u4 = reinterpret_cast<float4*>(u);
    float4* v4 = reinterpret_cast<float4*>(v);
    u4[idx * 2 + 0] = make_float4(uo[0], uo[1], uo[2], uo[3]);
    u4[idx * 2 + 1] = make_float4(uo[4], uo[5], uo[6], uo[7]);
    v4[idx * 2 + 0] = make_float4(vo[0], vo[1], vo[2], vo[3]);
    v4[idx * 2 + 1] = make_float4(vo[4], vo[5], vo[6], vo[7]);
}

// ---------------------------------------------------------------------------
// Kernel 2: out[b,i,j] = sigmoid(b2 + sum_k relu(u[b,i,k]+v[b,j,k]) * W2[k])
// One thread per output element. Writes coalesced; u row / W2 / b2 uniform.
// ---------------------------------------------------------------------------
__global__ __launch_bounds__(256) void out_kernel(
    const float* __restrict__ u, const float* __restrict__ v,
    const float* __restrict__ W2, const float* __restrict__ b2,
    float* __restrict__ out)
{
    const int row = blockIdx.y;                     // b*N + i  (uniform per block)
    const int j   = blockIdx.x * 256 + threadIdx.x; // [0, N)
    const int b   = row >> 9;                       // row / 512

    float ur[NH];
    #pragma unroll
    for (int k = 0; k < NH; ++k) ur[k] = u[row * NH + k];   // uniform -> s_load

    float w2[NH];
    #pragma unroll
    for (int k = 0; k < NH; ++k) w2[k] = W2[k];

    const float4* v4 = reinterpret_cast<const float4*>(v);
    const int vi = (b * NN + j) * 2;
    const float4 va = v4[vi];
    const float4 vb = v4[vi + 1];
    const float vv[NH] = {va.x, va.y, va.z, va.w, vb.x, vb.y, vb.z, vb.w};

    float acc = b2[0];
    #pragma unroll
    for (int k = 0; k < NH; ++k)
        acc = fmaf(fmaxf(ur[k] + vv[k], 0.f), w2[k], acc);

    out[(size_t)row * NN + j] = 1.0f / (1.0f + expf(-acc));
}

extern "C" void kernel_launch(void* const* d_in, const int* in_sizes, int n_in,
                              void* d_out, int out_size, void* d_ws, size_t ws_size,
                              hipStream_t stream) {
    const float* adj = (const float*)d_in[0];
    const float* emb = (const float*)d_in[1];
    const float* W1  = (const float*)d_in[2];
    const float* b1  = (const float*)d_in[3];
    const float* W2  = (const float*)d_in[4];
    const float* b2  = (const float*)d_in[5];
    float* out = (float*)d_out;

    float* u = (float*)d_ws;               // B*N*H floats
    float* v = u + NB * NN * NH;           // B*N*H floats (256 KB total in ws)

    uv_kernel<<<dim3(NB * NN / 256), 256, 0, stream>>>(adj, emb, W1, b1, u, v);
    out_kernel<<<dim3(NN / 256, NB * NN), 256, 0, stream>>>(u, v, W2, b2, out);
}

// Round 2
// 20.389 us; speedup vs baseline: 1.0762x; 1.0762x over previous
//
#include <hip/hip_runtime.h>
#include <math.h>

constexpr int NB = 8;    // batch
constexpr int NF = 32;   // features
constexpr int NN = 512;  // nodes
constexpr int NH = 8;    // hidden
constexpr int KCH = 32;  // column-sum chunks
constexpr int KROWS = NN / KCH;  // 16 rows per chunk

// ---------------------------------------------------------------------------
// Kernel 1: partial column sums of batch-0 adjacency.
//   part[c][n] = sum_{k in chunk c} adj[0,k,n]
// grid (NN/256, KCH) = 64 blocks; fully parallel, coalesced.
// ---------------------------------------------------------------------------
__global__ __launch_bounds__(256) void colsum_part_kernel(
    const float* __restrict__ adj, float* __restrict__ part)
{
    const int n = blockIdx.x * 256 + threadIdx.x;
    const int c = blockIdx.y;
    const float* p = adj + (size_t)c * KROWS * NN + n;
    float acc = 0.f;
    #pragma unroll
    for (int k = 0; k < KROWS; ++k)
        acc += p[(size_t)k * NN];
    part[c * NN + n] = acc;
}

// ---------------------------------------------------------------------------
// Kernel 2: per (b,n) precompute
//   u[b,n,k] = sum_f emb[b,f,n] * W1[f,k]
//   v[b,n,k] = sum_f emb[b,f,n] * W1[F+f,k] + sw[b,n]*W1[2F,k] + b1[k]
//   sw[b,n]  = (colsum0[n] - adj[b,n,n]) / (N-1)
// ---------------------------------------------------------------------------
__global__ __launch_bounds__(256) void uv_kernel(
    const float* __restrict__ adj, const float* __restrict__ emb,
    const float* __restrict__ W1, const float* __restrict__ b1,
    const float* __restrict__ part,
    float* __restrict__ u, float* __restrict__ v)
{
    const int idx = blockIdx.x * 256 + threadIdx.x;   // [0, B*N)
    const int b = idx / NN;
    const int n = idx % NN;

    // colsum0[n] from the 32 partials (coalesced in n)
    float cs = 0.f;
    #pragma unroll
    for (int c = 0; c < KCH; ++c)
        cs += part[c * NN + n];

    const float dg = adj[((size_t)b * NN + n) * NN + n];
    const float sw = (cs - dg) * (1.0f / (float)(NN - 1));

    float uo[NH], vo[NH];
    #pragma unroll
    for (int k = 0; k < NH; ++k) {
        uo[k] = 0.f;
        vo[k] = b1[k] + sw * W1[2 * NF * NH + k];
    }

    for (int f = 0; f < NF; ++f) {
        const float e = emb[((size_t)b * NF + f) * NN + n];   // coalesced in n
        #pragma unroll
        for (int k = 0; k < NH; ++k) {
            uo[k] = fmaf(e, W1[f * NH + k],        uo[k]);
            vo[k] = fmaf(e, W1[(NF + f) * NH + k], vo[k]);
        }
    }

    float4* u4 = reinterpret_cast<float4*>(u);
    float4* v4 = reinterpret_cast<float4*>(v);
    u4[idx * 2 + 0] = make_float4(uo[0], uo[1], uo[2], uo[3]);
    u4[idx * 2 + 1] = make_float4(uo[4], uo[5], uo[6], uo[7]);
    v4[idx * 2 + 0] = make_float4(vo[0], vo[1], vo[2], vo[3]);
    v4[idx * 2 + 1] = make_float4(vo[4], vo[5], vo[6], vo[7]);
}

// ---------------------------------------------------------------------------
// Kernel 3: out[b,i,j] = sigmoid(b2 + sum_k relu(u[b,i,k]+v[b,j,k]) * W2[k])
// One block per output row (b,i); each thread produces 2 adjacent j's,
// float2 store. u row / W2 / b2 are wave-uniform.
// ---------------------------------------------------------------------------
__global__ __launch_bounds__(256) void out_kernel(
    const float* __restrict__ u, const float* __restrict__ v,
    const float* __restrict__ W2, const float* __restrict__ b2,
    float* __restrict__ out)
{
    const int row = blockIdx.x;                     // b*N + i
    const int b   = row >> 9;                       // row / 512
    const int j0  = threadIdx.x * 2;

    float ur[NH];
    #pragma unroll
    for (int k = 0; k < NH; ++k) ur[k] = u[row * NH + k];

    float w2[NH];
    #pragma unroll
    for (int k = 0; k < NH; ++k) w2[k] = W2[k];
    const float bias = b2[0];

    const float4* v4 = reinterpret_cast<const float4*>(v);
    const int vi = (b * NN + j0) * 2;
    const float4 va0 = v4[vi + 0];
    const float4 vb0 = v4[vi + 1];
    const float4 va1 = v4[vi + 2];
    const float4 vb1 = v4[vi + 3];
    const float vv0[NH] = {va0.x, va0.y, va0.z, va0.w, vb0.x, vb0.y, vb0.z, vb0.w};
    const float vv1[NH] = {va1.x, va1.y, va1.z, va1.w, vb1.x, vb1.y, vb1.z, vb1.w};

    float acc0 = bias, acc1 = bias;
    #pragma unroll
    for (int k = 0; k < NH; ++k) {
        acc0 = fmaf(fmaxf(ur[k] + vv0[k], 0.f), w2[k], acc0);
        acc1 = fmaf(fmaxf(ur[k] + vv1[k], 0.f), w2[k], acc1);
    }

    float2 o;
    o.x = 1.0f / (1.0f + __expf(-acc0));
    o.y = 1.0f / (1.0f + __expf(-acc1));
    reinterpret_cast<float2*>(out + (size_t)row * NN)[threadIdx.x] = o;
}

extern "C" void kernel_launch(void* const* d_in, const int* in_sizes, int n_in,
                              void* d_out, int out_size, void* d_ws, size_t ws_size,
                              hipStream_t stream) {
    const float* adj = (const float*)d_in[0];
    const float* emb = (const float*)d_in[1];
    const float* W1  = (const float*)d_in[2];
    const float* b1  = (const float*)d_in[3];
    const float* W2  = (const float*)d_in[4];
    const float* b2  = (const float*)d_in[5];
    float* out = (float*)d_out;

    float* u    = (float*)d_ws;                 // B*N*H floats
    float* v    = u + NB * NN * NH;             // B*N*H floats
    float* part = v + NB * NN * NH;             // KCH*NN floats

    colsum_part_kernel<<<dim3(NN / 256, KCH), 256, 0, stream>>>(adj, part);
    uv_kernel<<<dim3(NB * NN / 256), 256, 0, stream>>>(adj, emb, W1, b1, part, u, v);
    out_kernel<<<dim3(NB * NN), 256, 0, stream>>>(u, v, W2, b2, out);
}